// Round 1
// 1141.982 us; speedup vs baseline: 1.5308x; 1.5308x over previous
//
#include <hip/hip_runtime.h>

// Fused windowed cross-attention for MI355X (gfx950) — v2.
// One block = one 8x8 window (4096 blocks), 512 threads = 8 waves (2 waves/SIMD).
// Wave wv owns GEMM rows [32*wv, 32*wv+32) == head wv's q/k/v slice, so the whole
// attention pipeline is wave-private (3 block barriers total).
// Weights are pre-packed to bf16 in MFMA-fragment order in d_ws by pack_w.

typedef __attribute__((ext_vector_type(8))) short bf16x8;   // 8 bf16 = 4 VGPRs (MFMA A/B)
typedef __attribute__((ext_vector_type(4))) short short4v;  // packed 4x bf16 LDS write
typedef __attribute__((ext_vector_type(4))) float floatx4;  // MFMA C/D

constexpr int kC  = 256;
constexpr int kH  = 252;
constexpr int kW  = 252;
constexpr int kHW = kH * kW;  // 63504
// softmax scale (hd^-0.5) folded with log2(e) for exp2
constexpr float kScaleLog2e = 0.17677669529663689f * 1.4426950408889634f;

__device__ __forceinline__ short f2bf(float f) {
  union { float f; unsigned u; } v; v.f = f;
  unsigned u = v.u + 0x7fffu + ((v.u >> 16) & 1u);  // RNE
  return (short)(u >> 16);
}

// ---------------- weight pre-pack: fp32 [o][c] -> bf16 fragment order ----------------
// Packed unit index: ((o>>4)*32 + (c>>3))*128 + (o&15)*8 + (c&7)
// A-fragment for row-tile t, k-chunk kc, lane r = 16B at (t*32+kc)*128 + r*8
// -> a wave's 64 lanes read 1KB fully contiguous.
__global__ void pack_w(const float* __restrict__ wq, const float* __restrict__ wkv,
                       const float* __restrict__ wp, short* __restrict__ dst) {
  const int o = blockIdx.x;      // 0..1023 global row
  const int c = threadIdx.x;     // 0..255
  const float* s; short* d; int ol;
  if (o < 256)      { s = wq;  ol = o;       d = dst; }
  else if (o < 768) { s = wkv; ol = o - 256; d = dst + 65536; }
  else              { s = wp;  ol = o - 768; d = dst + 196608; }
  d[((ol >> 4) * 32 + (c >> 3)) * 128 + (ol & 15) * 8 + (c & 7)] = f2bf(s[ol * 256 + c]);
}

// Swizzled LDS layouts (units = bf16):
//  SW256 (256 rows r, 64 cols): idx = (r>>3)*512  + col*8 + (r&7)   (XQ,XK,QS,KS/AO)
//  SWV   (64 rows m, 256 cols): idx = (m>>3)*2048 + col*8 + (m&7)   (VS)
//  SWP   (64 rows m, 64 cols) : idx = (m>>3)*512  + col*8 + (m&7)   (P, per-wave)

__global__ __launch_bounds__(512, 2) void win_attn(
    const float* __restrict__ xq, const float* __restrict__ xkv,
    const short* __restrict__ wpk, const float* __restrict__ bproj,
    float* __restrict__ out) {
  extern __shared__ short lds[];
  short* XQ = lds;               // 16384 units: x_q window SW256(c,l); later P waves 0-3
  short* XK = lds + 16384;       // x_kv window SW256(c,l); later P waves 4-7
  short* QS = lds + 32768;       // q, SW256(o,l)          (wave-private rows)
  short* KS = lds + 49152;       // k, SW256(o,m); later AO SW256(c,l)
  short* VS = lds + 65536;       // v, SWV(m,c)            (wave-private cols)
  short* AO = KS;

  const short* WQp  = wpk;            // 256x256
  const short* WKVp = wpk + 65536;    // 512x256 (k rows = tiles 0..15, v rows = tiles 16..31)
  const short* WPp  = wpk + 196608;   // 256x256

  const int n  = blockIdx.x;
  const int b  = n >> 10;
  const int h0 = ((n >> 5) & 31) * 8;
  const int w0 = (n & 31) * 8;
  const int tid  = threadIdx.x;
  const int wv   = tid >> 6;     // 0..7 — wave id == head id
  const int lane = tid & 63;
  const int quad = lane >> 4;
  const int r    = lane & 15;
  const floatx4 vzero = {0.f, 0.f, 0.f, 0.f};

  // ---------- stage x_q / x_kv window into LDS (bf16, SW256) ----------
  // Thread covers a (4-channel, 4-pixel) tile: float4 loads, short4v LDS writes.
  {
    const int pg   = tid & 15;           // pixel group: row = pg>>1, half-row = pg&1
    const int cq   = tid >> 4;           // 0..31 channel quad
    const int row  = pg >> 1, half = pg & 1;
    const int hh   = h0 + row;
    const int ww   = w0 + half * 4;
    const bool inb = (hh < kH) && (ww < kW);   // 4-pixel group never straddles the edge
    const int pix  = hh * kW + ww;
    #pragma unroll
    for (int i = 0; i < 2; ++i) {
      const int c0 = (cq + 32 * i) << 2;       // 4 consecutive channels
      const int gi = (b * kC + c0) * kHW + pix;
      float4 a0 = {0,0,0,0}, a1 = a0, a2 = a0, a3 = a0;
      float4 k0 = a0, k1 = a0, k2 = a0, k3 = a0;
      if (inb) {
        a0 = *(const float4*)(xq  + gi);
        a1 = *(const float4*)(xq  + gi + kHW);
        a2 = *(const float4*)(xq  + gi + 2 * kHW);
        a3 = *(const float4*)(xq  + gi + 3 * kHW);
        k0 = *(const float4*)(xkv + gi);
        k1 = *(const float4*)(xkv + gi + kHW);
        k2 = *(const float4*)(xkv + gi + 2 * kHW);
        k3 = *(const float4*)(xkv + gi + 3 * kHW);
      }
      const int ub = (c0 >> 3) * 512 + (c0 & 7);
      const int l0 = (row * 8 + half * 4) * 8;   // unit offset of first pixel
      short4v q0 = {f2bf(a0.x), f2bf(a1.x), f2bf(a2.x), f2bf(a3.x)};
      short4v q1 = {f2bf(a0.y), f2bf(a1.y), f2bf(a2.y), f2bf(a3.y)};
      short4v q2 = {f2bf(a0.z), f2bf(a1.z), f2bf(a2.z), f2bf(a3.z)};
      short4v q3 = {f2bf(a0.w), f2bf(a1.w), f2bf(a2.w), f2bf(a3.w)};
      *(short4v*)(XQ + ub + l0)      = q0;
      *(short4v*)(XQ + ub + l0 + 8)  = q1;
      *(short4v*)(XQ + ub + l0 + 16) = q2;
      *(short4v*)(XQ + ub + l0 + 24) = q3;
      short4v p0 = {f2bf(k0.x), f2bf(k1.x), f2bf(k2.x), f2bf(k3.x)};
      short4v p1 = {f2bf(k0.y), f2bf(k1.y), f2bf(k2.y), f2bf(k3.y)};
      short4v p2 = {f2bf(k0.z), f2bf(k1.z), f2bf(k2.z), f2bf(k3.z)};
      short4v p3 = {f2bf(k0.w), f2bf(k1.w), f2bf(k2.w), f2bf(k3.w)};
      *(short4v*)(XK + ub + l0)      = p0;
      *(short4v*)(XK + ub + l0 + 8)  = p1;
      *(short4v*)(XK + ub + l0 + 16) = p2;
      *(short4v*)(XK + ub + l0 + 24) = p3;
    }
  }
  __syncthreads();   // barrier A: staging complete

  // ---------- q = w_q @ xq -> QS (rows 32wv..32wv+31, wave-private) ----------
  {
    floatx4 acc[2][4];
    #pragma unroll
    for (int i = 0; i < 2; ++i)
      #pragma unroll
      for (int j = 0; j < 4; ++j) acc[i][j] = vzero;
    #pragma unroll 4
    for (int k0 = 0; k0 < 256; k0 += 32) {
      const int kc = (k0 >> 3) + quad;
      bf16x8 a[2], bb[4];
      #pragma unroll
      for (int mt = 0; mt < 2; ++mt)
        a[mt] = *(const bf16x8*)(WQp + ((2 * wv + mt) * 32 + kc) * 128 + r * 8);
      #pragma unroll
      for (int nt = 0; nt < 4; ++nt)
        bb[nt] = *(const bf16x8*)(XQ + kc * 512 + (16 * nt + r) * 8);
      #pragma unroll
      for (int mt = 0; mt < 2; ++mt)
        #pragma unroll
        for (int nt = 0; nt < 4; ++nt)
          acc[mt][nt] = __builtin_amdgcn_mfma_f32_16x16x32_bf16(a[mt], bb[nt], acc[mt][nt], 0, 0, 0);
    }
    #pragma unroll
    for (int mt = 0; mt < 2; ++mt) {
      const int ob = 32 * wv + 16 * mt + quad * 4;
      #pragma unroll
      for (int nt = 0; nt < 4; ++nt) {
        const int l = 16 * nt + r;
        short4v v4 = { f2bf(acc[mt][nt][0]), f2bf(acc[mt][nt][1]),
                       f2bf(acc[mt][nt][2]), f2bf(acc[mt][nt][3]) };
        *(short4v*)(QS + (ob >> 3) * 512 + l * 8 + (ob & 7)) = v4;
      }
    }
  }

  // ---------- k = w_kv[0:256] @ xkv -> KS (wave-private rows) ----------
  {
    floatx4 acc[2][4];
    #pragma unroll
    for (int i = 0; i < 2; ++i)
      #pragma unroll
      for (int j = 0; j < 4; ++j) acc[i][j] = vzero;
    #pragma unroll 4
    for (int k0 = 0; k0 < 256; k0 += 32) {
      const int kc = (k0 >> 3) + quad;
      bf16x8 a[2], bb[4];
      #pragma unroll
      for (int mt = 0; mt < 2; ++mt)
        a[mt] = *(const bf16x8*)(WKVp + ((2 * wv + mt) * 32 + kc) * 128 + r * 8);
      #pragma unroll
      for (int nt = 0; nt < 4; ++nt)
        bb[nt] = *(const bf16x8*)(XK + kc * 512 + (16 * nt + r) * 8);
      #pragma unroll
      for (int mt = 0; mt < 2; ++mt)
        #pragma unroll
        for (int nt = 0; nt < 4; ++nt)
          acc[mt][nt] = __builtin_amdgcn_mfma_f32_16x16x32_bf16(a[mt], bb[nt], acc[mt][nt], 0, 0, 0);
    }
    #pragma unroll
    for (int mt = 0; mt < 2; ++mt) {
      const int ob = 32 * wv + 16 * mt + quad * 4;
      #pragma unroll
      for (int nt = 0; nt < 4; ++nt) {
        const int m = 16 * nt + r;
        short4v v4 = { f2bf(acc[mt][nt][0]), f2bf(acc[mt][nt][1]),
                       f2bf(acc[mt][nt][2]), f2bf(acc[mt][nt][3]) };
        *(short4v*)(KS + (ob >> 3) * 512 + m * 8 + (ob & 7)) = v4;
      }
    }
  }

  // ---------- v = w_kv[256:512] @ xkv -> VS (wave-private cols) ----------
  {
    floatx4 acc[2][4];
    #pragma unroll
    for (int i = 0; i < 2; ++i)
      #pragma unroll
      for (int j = 0; j < 4; ++j) acc[i][j] = vzero;
    #pragma unroll 4
    for (int k0 = 0; k0 < 256; k0 += 32) {
      const int kc = (k0 >> 3) + quad;
      bf16x8 a[2], bb[4];
      #pragma unroll
      for (int mt = 0; mt < 2; ++mt)
        a[mt] = *(const bf16x8*)(WKVp + ((16 + 2 * wv + mt) * 32 + kc) * 128 + r * 8);
      #pragma unroll
      for (int nt = 0; nt < 4; ++nt)
        bb[nt] = *(const bf16x8*)(XK + kc * 512 + (16 * nt + r) * 8);
      #pragma unroll
      for (int mt = 0; mt < 2; ++mt)
        #pragma unroll
        for (int nt = 0; nt < 4; ++nt)
          acc[mt][nt] = __builtin_amdgcn_mfma_f32_16x16x32_bf16(a[mt], bb[nt], acc[mt][nt], 0, 0, 0);
    }
    #pragma unroll
    for (int mt = 0; mt < 2; ++mt) {
      const int cb2 = 32 * wv + 16 * mt + quad * 4;
      #pragma unroll
      for (int nt = 0; nt < 4; ++nt) {
        const int m  = 16 * nt + r;
        const int vb = (m >> 3) * 2048 + (m & 7);
        VS[vb + (cb2 + 0) * 8] = f2bf(acc[mt][nt][0]);
        VS[vb + (cb2 + 1) * 8] = f2bf(acc[mt][nt][1]);
        VS[vb + (cb2 + 2) * 8] = f2bf(acc[mt][nt][2]);
        VS[vb + (cb2 + 3) * 8] = f2bf(acc[mt][nt][3]);
      }
    }
  }

  // ---------- attention, head h = wv (all operands wave-private) ----------
  const int h = wv;
  // S = q_h^T @ k_h (M=l=64, N=m=64, K=d=32)
  floatx4 s[4][4];
  {
    bf16x8 aq[4], bk[4];
    #pragma unroll
    for (int mt = 0; mt < 4; ++mt)
      aq[mt] = *(const bf16x8*)(QS + (4 * h + quad) * 512 + (16 * mt + r) * 8);
    #pragma unroll
    for (int nt = 0; nt < 4; ++nt)
      bk[nt] = *(const bf16x8*)(KS + (4 * h + quad) * 512 + (16 * nt + r) * 8);
    #pragma unroll
    for (int mt = 0; mt < 4; ++mt)
      #pragma unroll
      for (int nt = 0; nt < 4; ++nt)
        s[mt][nt] = __builtin_amdgcn_mfma_f32_16x16x32_bf16(aq[mt], bk[nt], vzero, 0, 0, 0);
  }

  // softmax over m (row l = 4*quad+reg+16mt; m spread over 4 nt-tiles x 16 lanes)
  float rinv[4][4];
  #pragma unroll
  for (int mt = 0; mt < 4; ++mt) {
    #pragma unroll
    for (int reg = 0; reg < 4; ++reg) {
      float mx = fmaxf(fmaxf(s[mt][0][reg], s[mt][1][reg]),
                       fmaxf(s[mt][2][reg], s[mt][3][reg]));
      mx = fmaxf(mx, __shfl_xor(mx, 1));
      mx = fmaxf(mx, __shfl_xor(mx, 2));
      mx = fmaxf(mx, __shfl_xor(mx, 4));
      mx = fmaxf(mx, __shfl_xor(mx, 8));
      float sum = 0.f;
      #pragma unroll
      for (int nt = 0; nt < 4; ++nt) {
        float e = exp2f((s[mt][nt][reg] - mx) * kScaleLog2e);
        s[mt][nt][reg] = e;   // unnormalized; normalize at PV epilogue
        sum += e;
      }
      sum += __shfl_xor(sum, 1);
      sum += __shfl_xor(sum, 2);
      sum += __shfl_xor(sum, 4);
      sum += __shfl_xor(sum, 8);
      rinv[mt][reg] = 1.0f / sum;
    }
  }

  __syncthreads();   // barrier B: all waves done reading XQ/XK -> P may overwrite

  // P -> LDS (SWP: row=m, col=l), per-wave 8KB buffer over the dead XQ/XK region
  short* myP = lds + wv * 4096;
  #pragma unroll
  for (int nt = 0; nt < 4; ++nt) {
    const int m  = 16 * nt + r;
    const int pb = (m >> 3) * 512 + (m & 7);
    #pragma unroll
    for (int mt = 0; mt < 4; ++mt) {
      const int lb = 16 * mt + quad * 4;
      myP[pb + (lb + 0) * 8] = f2bf(s[mt][nt][0]);
      myP[pb + (lb + 1) * 8] = f2bf(s[mt][nt][1]);
      myP[pb + (lb + 2) * 8] = f2bf(s[mt][nt][2]);
      myP[pb + (lb + 3) * 8] = f2bf(s[mt][nt][3]);
    }
  }

  // O = P @ v_h (M=l=64, N=d=32, K=m=64)
  floatx4 o2[4][2];
  #pragma unroll
  for (int i = 0; i < 4; ++i) { o2[i][0] = vzero; o2[i][1] = vzero; }
  #pragma unroll
  for (int kt = 0; kt < 2; ++kt) {
    bf16x8 ap[4], bv[2];
    #pragma unroll
    for (int mt = 0; mt < 4; ++mt)
      ap[mt] = *(const bf16x8*)(myP + (4 * kt + quad) * 512 + (16 * mt + r) * 8);
    #pragma unroll
    for (int nt = 0; nt < 2; ++nt)
      bv[nt] = *(const bf16x8*)(VS + (4 * kt + quad) * 2048 + (32 * h + 16 * nt + r) * 8);
    #pragma unroll
    for (int mt = 0; mt < 4; ++mt)
      #pragma unroll
      for (int nt = 0; nt < 2; ++nt)
        o2[mt][nt] = __builtin_amdgcn_mfma_f32_16x16x32_bf16(ap[mt], bv[nt], o2[mt][nt], 0, 0, 0);
  }

  // normalize + store AO into KS region (rows 32h..32h+31, wave-private)
  #pragma unroll
  for (int nt = 0; nt < 2; ++nt) {
    const int c  = 32 * h + 16 * nt + r;
    const int ab = (c >> 3) * 512 + (c & 7);
    #pragma unroll
    for (int mt = 0; mt < 4; ++mt) {
      const int lb = 16 * mt + quad * 4;
      AO[ab + (lb + 0) * 8] = f2bf(o2[mt][nt][0] * rinv[mt][0]);
      AO[ab + (lb + 1) * 8] = f2bf(o2[mt][nt][1] * rinv[mt][1]);
      AO[ab + (lb + 2) * 8] = f2bf(o2[mt][nt][2] * rinv[mt][2]);
      AO[ab + (lb + 3) * 8] = f2bf(o2[mt][nt][3] * rinv[mt][3]);
    }
  }
  __syncthreads();   // barrier C: AO complete for all heads

  // ---------- final projection: out = w_proj @ AO + b_proj, window scatter ----------
  {
    floatx4 acc[2][4];
    #pragma unroll
    for (int i = 0; i < 2; ++i)
      #pragma unroll
      for (int j = 0; j < 4; ++j) acc[i][j] = vzero;
    #pragma unroll 4
    for (int k0 = 0; k0 < 256; k0 += 32) {
      const int kc = (k0 >> 3) + quad;
      bf16x8 a[2], bb[4];
      #pragma unroll
      for (int mt = 0; mt < 2; ++mt)
        a[mt] = *(const bf16x8*)(WPp + ((2 * wv + mt) * 32 + kc) * 128 + r * 8);
      #pragma unroll
      for (int nt = 0; nt < 4; ++nt)
        bb[nt] = *(const bf16x8*)(AO + kc * 512 + (16 * nt + r) * 8);
      #pragma unroll
      for (int mt = 0; mt < 2; ++mt)
        #pragma unroll
        for (int nt = 0; nt < 4; ++nt)
          acc[mt][nt] = __builtin_amdgcn_mfma_f32_16x16x32_bf16(a[mt], bb[nt], acc[mt][nt], 0, 0, 0);
    }
    #pragma unroll
    for (int mt = 0; mt < 2; ++mt) {
      const int ob = 32 * wv + 16 * mt + quad * 4;
      const float b0 = bproj[ob + 0], b1 = bproj[ob + 1];
      const float b2 = bproj[ob + 2], b3 = bproj[ob + 3];
      #pragma unroll
      for (int nt = 0; nt < 4; ++nt) {
        const int l  = 16 * nt + r;
        const int hh = h0 + (l >> 3);
        const int ww = w0 + (l & 7);
        if (hh < kH && ww < kW) {
          const int gi = (b * kC + ob) * kHW + hh * kW + ww;
          out[gi]           = acc[mt][nt][0] + b0;
          out[gi + kHW]     = acc[mt][nt][1] + b1;
          out[gi + 2 * kHW] = acc[mt][nt][2] + b2;
          out[gi + 3 * kHW] = acc[mt][nt][3] + b3;
        }
      }
    }
  }
}

extern "C" void kernel_launch(void* const* d_in, const int* in_sizes, int n_in,
                              void* d_out, int out_size, void* d_ws, size_t ws_size,
                              hipStream_t stream) {
  const float* xq    = (const float*)d_in[0];
  const float* xkv   = (const float*)d_in[1];
  const float* wq    = (const float*)d_in[2];
  const float* wkv   = (const float*)d_in[3];
  const float* wproj = (const float*)d_in[4];
  const float* bproj = (const float*)d_in[5];
  float* out = (float*)d_out;
  short* wpk = (short*)d_ws;   // 512 KB packed bf16 weights

  // Pre-pack weights to bf16 fragment order (re-run every launch; workspace may be poisoned).
  pack_w<<<1024, 256, 0, stream>>>(wq, wkv, wproj, wpk);

  // 160KB dynamic LDS per block (1 block/CU, 8 waves -> 2 waves/SIMD).
  (void)hipFuncSetAttribute((const void*)win_attn,
                            hipFuncAttributeMaxDynamicSharedMemorySize, 163840);
  win_attn<<<4096, 512, 163840, stream>>>(xq, xkv, wpk, bproj, out);
}

// Round 3
// 823.510 us; speedup vs baseline: 2.1228x; 1.3867x over previous
//
#include <hip/hip_runtime.h>
#include <hip/hip_bf16.h>

// Fused windowed cross-attention for MI355X (gfx950) — v4.
// One block = one 8x8 window (4096 blocks), 512 threads = 8 waves; wave == head.
// LDS cut to 64KB (XQ+XK staging only) -> 2 blocks/CU -> 4 waves/SIMD.
// q/k/v/P never touch LDS: MFMA C-layout -> A/B-fragment layout is done in-register
// with permlane32_swap + permlane16_swap (via compiler builtins so VALU->permlane
// hazard NOPs are inserted — the v3 raw-asm version read stale registers).

typedef __attribute__((ext_vector_type(8))) short bf16x8;   // 8 bf16 = 4 VGPRs (MFMA A/B)
typedef __attribute__((ext_vector_type(4))) short short4v;  // packed 4x bf16 LDS write
typedef __attribute__((ext_vector_type(4))) float floatx4;  // MFMA C/D
typedef __attribute__((ext_vector_type(2))) unsigned uint2v;

constexpr int kC  = 256;
constexpr int kH  = 252;
constexpr int kW  = 252;
constexpr int kHW = kH * kW;  // 63504
// softmax scale (hd^-0.5) folded with log2(e) for exp2
constexpr float kScaleLog2e = 0.17677669529663689f * 1.4426950408889634f;

__device__ __forceinline__ short f2bf(float f) {
  union { float f; unsigned u; } v; v.f = f;
  unsigned u = v.u + 0x7fffu + ((v.u >> 16) & 1u);  // RNE
  return (short)(u >> 16);
}

// ---------------- weight pre-pack: fp32 [o][c] -> bf16 fragment order ----------------
// Packed unit index: ((o>>4)*32 + (c>>3))*128 + (o&15)*8 + (c&7)
// Fragment (tile t, k-chunk kc8, lane r) = 16B at (t*32+kc8)*128 + r*8.
// The same fragment serves as MFMA A-operand (rows o) or B-operand (cols o).
__global__ void pack_w(const float* __restrict__ wq, const float* __restrict__ wkv,
                       const float* __restrict__ wp, short* __restrict__ dst) {
  const int o = blockIdx.x;      // 0..1023 global row
  const int c = threadIdx.x;     // 0..255
  const float* s; short* d; int ol;
  if (o < 256)      { s = wq;  ol = o;       d = dst; }
  else if (o < 768) { s = wkv; ol = o - 256; d = dst + 65536; }
  else              { s = wp;  ol = o - 768; d = dst + 196608; }
  d[((ol >> 4) * 32 + (c >> 3)) * 128 + (ol & 15) * 8 + (c & 7)] = f2bf(s[ol * 256 + c]);
}

// pack two f32 to one u32 of 2x bf16 (lo = a, hi = b) — compiler-visible cvt_pk
__device__ __forceinline__ unsigned cvtpk(float a, float b) {
  union { __hip_bfloat162 h; unsigned u; } v;
  v.h = __float22bfloat162_rn(make_float2(a, b));
  return v.u;
}

// quad-granularity redistribution core:
//   in : x = packed word p of row-group X (rows 0..15 via 4Q+g), y = same word of Y (16..31)
//   out: x = frag word holding rows {8Q+2p, 8Q+2p+1}: lanes {X.q0, X.q2, Y.q0, Y.q2}
//        y = frag word holding rows {8Q+2p+4, ...}:   lanes {X.q1, X.q3, Y.q1, Y.q3}
__device__ __forceinline__ void plswap(unsigned &x, unsigned &y) {
#if __has_builtin(__builtin_amdgcn_permlane32_swap)
  // permlane32_swap: t0 = {x.q0,x.q1,y.q0,y.q1}, t1 = {x.q2,x.q3,y.q2,y.q3}
  // permlane16_swap: u0 = {t0.q0,t1.q0,t0.q2,t1.q2} = {x.q0,x.q2,y.q0,y.q2}
  //                  u1 = {t0.q1,t1.q1,t0.q3,t1.q3} = {x.q1,x.q3,y.q1,y.q3}
  uint2v t = __builtin_amdgcn_permlane32_swap(x, y, false, false);
  uint2v u = __builtin_amdgcn_permlane16_swap(t[0], t[1], false, false);
  x = u[0]; y = u[1];
#else
  // __shfl fallback — identical mapping, independent of permlane semantics
  const int lane = (int)(threadIdx.x & 63);
  const int r = lane & 15, Q = lane >> 4;
  const int s0 = ((Q & 1) << 5) + r;          // source lane for even source quads
  unsigned xa = __shfl(x, s0), xb = __shfl(x, s0 + 16);
  unsigned ya = __shfl(y, s0), yb = __shfl(y, s0 + 16);
  unsigned nx = (Q < 2) ? xa : ya;
  unsigned ny = (Q < 2) ? xb : yb;
  x = nx; y = ny;
#endif
}

// C-layout pair (X = rows 0..15 of a 32-row group, Y = rows 16..31, cols fixed 16)
// -> A/B fragment: lane(Q,r) holds elem[col=r][row = 8*Q + j], j=0..7.
__device__ __forceinline__ bf16x8 redist(floatx4 X, floatx4 Y) {
  unsigned w0 = cvtpk(X[0], X[1]);
  unsigned w1 = cvtpk(X[2], X[3]);
  unsigned w2 = cvtpk(Y[0], Y[1]);
  unsigned w3 = cvtpk(Y[2], Y[3]);
  plswap(w0, w2);   // w0 = frag word0 (j=0,1), w2 = frag word2 (j=4,5)
  plswap(w1, w3);   // w1 = frag word1 (j=2,3), w3 = frag word3 (j=6,7)
  union { unsigned u[4]; bf16x8 v; } r;
  r.u[0] = w0; r.u[1] = w1; r.u[2] = w2; r.u[3] = w3;
  return r.v;
}

// GEMM: acc[2][4] += Wpacked(tiles tile0,tile0+1) @ X_lds (SW256 layout, 64 cols)
__device__ __forceinline__ void gemm_wx(const short* __restrict__ Wp, int tile0,
                                        const short* __restrict__ X,
                                        int quad, int r, floatx4 acc[2][4]) {
  #pragma unroll 4
  for (int kc8 = quad; kc8 < 32; kc8 += 4) {
    bf16x8 a[2], bb[4];
    #pragma unroll
    for (int mt = 0; mt < 2; ++mt)
      a[mt] = *(const bf16x8*)(Wp + ((tile0 + mt) * 32 + kc8) * 128 + r * 8);
    #pragma unroll
    for (int nt = 0; nt < 4; ++nt)
      bb[nt] = *(const bf16x8*)(X + kc8 * 512 + (16 * nt + r) * 8);
    #pragma unroll
    for (int mt = 0; mt < 2; ++mt)
      #pragma unroll
      for (int nt = 0; nt < 4; ++nt)
        acc[mt][nt] = __builtin_amdgcn_mfma_f32_16x16x32_bf16(a[mt], bb[nt], acc[mt][nt], 0, 0, 0);
  }
}

// GEMM (transposed): acc[4][2] += X_lds^T @ Wpacked^T(tiles tile0,tile0+1)
// A-frag rows = the 64 LDS columns; B = packed weight frag used as B-operand.
__device__ __forceinline__ void gemm_xw(const short* __restrict__ X,
                                        const short* __restrict__ Wp, int tile0,
                                        int quad, int r, floatx4 acc[4][2]) {
  #pragma unroll 4
  for (int kc8 = quad; kc8 < 32; kc8 += 4) {
    bf16x8 av[4], bw[2];
    #pragma unroll
    for (int mt = 0; mt < 4; ++mt)
      av[mt] = *(const bf16x8*)(X + kc8 * 512 + (16 * mt + r) * 8);
    #pragma unroll
    for (int nt = 0; nt < 2; ++nt)
      bw[nt] = *(const bf16x8*)(Wp + ((tile0 + nt) * 32 + kc8) * 128 + r * 8);
    #pragma unroll
    for (int mt = 0; mt < 4; ++mt)
      #pragma unroll
      for (int nt = 0; nt < 2; ++nt)
        acc[mt][nt] = __builtin_amdgcn_mfma_f32_16x16x32_bf16(av[mt], bw[nt], acc[mt][nt], 0, 0, 0);
  }
}

// LDS layout SW256 (256 rows r, 64 cols): idx = (r>>3)*512 + col*8 + (r&7)

__global__ __launch_bounds__(512, 4) void win_attn(
    const float* __restrict__ xq, const float* __restrict__ xkv,
    const short* __restrict__ wpk, const float* __restrict__ bproj,
    float* __restrict__ out) {
  extern __shared__ short lds[];
  short* XQ = lds;               // 16384 units: x_q window SW256(c,l); later AO
  short* XK = lds + 16384;       // x_kv window SW256(c,l)
  short* AO = lds;               // attention output, SW256(c,l)

  const short* WQp  = wpk;            // 256x256 (q)
  const short* WKVp = wpk + 65536;    // 512x256 (k = tiles 0..15, v = tiles 16..31)
  const short* WPp  = wpk + 196608;   // 256x256 (proj)

  // XCD-aware swizzle: 4096 blocks = 8 XCDs x 512; adjacent windows share HBM lines.
  const int bid = blockIdx.x;
  const int n   = ((bid & 7) << 9) | (bid >> 3);
  const int b  = n >> 10;
  const int h0 = ((n >> 5) & 31) * 8;
  const int w0 = (n & 31) * 8;
  const int tid  = threadIdx.x;
  const int wv   = tid >> 6;     // 0..7 — wave id == head id
  const int lane = tid & 63;
  const int quad = lane >> 4;
  const int r    = lane & 15;
  const floatx4 vzero = {0.f, 0.f, 0.f, 0.f};

  // ---------- stage x_q / x_kv window into LDS (bf16, SW256) ----------
  {
    const int pg   = tid & 15;           // pixel group
    const int cq   = tid >> 4;           // 0..31 channel quad
    const int row  = pg >> 1, half = pg & 1;
    const int hh   = h0 + row;
    const int ww   = w0 + half * 4;
    const bool inb = (hh < kH) && (ww < kW);
    const int pix  = hh * kW + ww;
    #pragma unroll
    for (int i = 0; i < 2; ++i) {
      const int c0 = (cq + 32 * i) << 2;
      const int gi = (b * kC + c0) * kHW + pix;
      float4 a0 = {0,0,0,0}, a1 = a0, a2 = a0, a3 = a0;
      float4 k0 = a0, k1 = a0, k2 = a0, k3 = a0;
      if (inb) {
        a0 = *(const float4*)(xq  + gi);
        a1 = *(const float4*)(xq  + gi + kHW);
        a2 = *(const float4*)(xq  + gi + 2 * kHW);
        a3 = *(const float4*)(xq  + gi + 3 * kHW);
        k0 = *(const float4*)(xkv + gi);
        k1 = *(const float4*)(xkv + gi + kHW);
        k2 = *(const float4*)(xkv + gi + 2 * kHW);
        k3 = *(const float4*)(xkv + gi + 3 * kHW);
      }
      const int ub = (c0 >> 3) * 512 + (c0 & 7);
      const int l0 = (row * 8 + half * 4) * 8;
      short4v q0 = {f2bf(a0.x), f2bf(a1.x), f2bf(a2.x), f2bf(a3.x)};
      short4v q1 = {f2bf(a0.y), f2bf(a1.y), f2bf(a2.y), f2bf(a3.y)};
      short4v q2 = {f2bf(a0.z), f2bf(a1.z), f2bf(a2.z), f2bf(a3.z)};
      short4v q3 = {f2bf(a0.w), f2bf(a1.w), f2bf(a2.w), f2bf(a3.w)};
      *(short4v*)(XQ + ub + l0)      = q0;
      *(short4v*)(XQ + ub + l0 + 8)  = q1;
      *(short4v*)(XQ + ub + l0 + 16) = q2;
      *(short4v*)(XQ + ub + l0 + 24) = q3;
      short4v p0 = {f2bf(k0.x), f2bf(k1.x), f2bf(k2.x), f2bf(k3.x)};
      short4v p1 = {f2bf(k0.y), f2bf(k1.y), f2bf(k2.y), f2bf(k3.y)};
      short4v p2 = {f2bf(k0.z), f2bf(k1.z), f2bf(k2.z), f2bf(k3.z)};
      short4v p3 = {f2bf(k0.w), f2bf(k1.w), f2bf(k2.w), f2bf(k3.w)};
      *(short4v*)(XK + ub + l0)      = p0;
      *(short4v*)(XK + ub + l0 + 8)  = p1;
      *(short4v*)(XK + ub + l0 + 16) = p2;
      *(short4v*)(XK + ub + l0 + 24) = p3;
    }
  }
  __syncthreads();   // barrier A: staging complete

  // ---------- k = w_kv[0:256] @ xkv  -> register fragments kf ----------
  // C-layout: k[d = 16mt+4quad+reg][m = 16nt+r]  ->  kf[nt]: [m=16nt+r][d=8Q+j]
  bf16x8 kf[4];
  {
    floatx4 acc[2][4];
    #pragma unroll
    for (int i = 0; i < 2; ++i)
      #pragma unroll
      for (int j = 0; j < 4; ++j) acc[i][j] = vzero;
    gemm_wx(WKVp, 2 * wv, XK, quad, r, acc);
    #pragma unroll
    for (int nt = 0; nt < 4; ++nt) kf[nt] = redist(acc[0][nt], acc[1][nt]);
  }

  // ---------- q = w_q @ xq  -> register fragments qf ----------
  bf16x8 qf[4];
  {
    floatx4 acc[2][4];
    #pragma unroll
    for (int i = 0; i < 2; ++i)
      #pragma unroll
      for (int j = 0; j < 4; ++j) acc[i][j] = vzero;
    gemm_wx(WQp, 2 * wv, XQ, quad, r, acc);
    #pragma unroll
    for (int nt = 0; nt < 4; ++nt) qf[nt] = redist(acc[0][nt], acc[1][nt]);
  }

  // ---------- S' = K^T q = S^T  (rows m, cols l; K-dim = d = 32, single step) ----------
  floatx4 sp[4][4];   // sp[mt][lt]: m = 16mt+4quad+reg, l = 16lt+r
  #pragma unroll
  for (int mt = 0; mt < 4; ++mt)
    #pragma unroll
    for (int lt = 0; lt < 4; ++lt)
      sp[mt][lt] = __builtin_amdgcn_mfma_f32_16x16x32_bf16(kf[mt], qf[lt], vzero, 0, 0, 0);

  // ---------- softmax over m (16 in-lane values + 2 cross-lane steps per l) ----------
  float rinv[4];
  #pragma unroll
  for (int lt = 0; lt < 4; ++lt) {
    float mx = sp[0][lt][0];
    #pragma unroll
    for (int mt = 0; mt < 4; ++mt)
      #pragma unroll
      for (int g = 0; g < 4; ++g) mx = fmaxf(mx, sp[mt][lt][g]);
    mx = fmaxf(mx, __shfl_xor(mx, 16));
    mx = fmaxf(mx, __shfl_xor(mx, 32));
    float sum = 0.f;
    #pragma unroll
    for (int mt = 0; mt < 4; ++mt)
      #pragma unroll
      for (int g = 0; g < 4; ++g) {
        float e = exp2f((sp[mt][lt][g] - mx) * kScaleLog2e);
        sp[mt][lt][g] = e;
        sum += e;
      }
    sum += __shfl_xor(sum, 16);
    sum += __shfl_xor(sum, 32);
    rinv[lt] = 1.0f / sum;
  }

  // ---------- P fragments (normalized in f32, then packed+permuted) ----------
  // ap[lt][kt]: A[l = 16lt+r][m = 32kt + 8Q + j]
  bf16x8 ap[4][2];
  #pragma unroll
  for (int lt = 0; lt < 4; ++lt)
    #pragma unroll
    for (int kt = 0; kt < 2; ++kt) {
      floatx4 X, Y;
      #pragma unroll
      for (int g = 0; g < 4; ++g) {
        X[g] = sp[2 * kt][lt][g] * rinv[lt];
        Y[g] = sp[2 * kt + 1][lt][g] * rinv[lt];
      }
      ap[lt][kt] = redist(X, Y);
    }

  // ---------- v^T = xkv^T @ w_kv[256:512]^T  -> register fragments vf ----------
  // C-layout: v^T[m = 16mt+4quad+reg][dloc = 16nt2+r] -> vf[nt2][kt]: B[m=32kt+8Q+j][dloc=16nt2+r]
  bf16x8 vf[2][2];
  {
    floatx4 acc[4][2];
    #pragma unroll
    for (int i = 0; i < 4; ++i)
      #pragma unroll
      for (int j = 0; j < 2; ++j) acc[i][j] = vzero;
    gemm_xw(XK, WKVp, 16 + 2 * wv, quad, r, acc);
    #pragma unroll
    for (int nt2 = 0; nt2 < 2; ++nt2)
      #pragma unroll
      for (int kt = 0; kt < 2; ++kt)
        vf[nt2][kt] = redist(acc[2 * kt][nt2], acc[2 * kt + 1][nt2]);
  }

  // ---------- O = P @ v_h  (M = l = 64, N = dloc = 32, K = m = 64) ----------
  floatx4 o2[4][2];
  #pragma unroll
  for (int i = 0; i < 4; ++i) { o2[i][0] = vzero; o2[i][1] = vzero; }
  #pragma unroll
  for (int kt = 0; kt < 2; ++kt)
    #pragma unroll
    for (int lt = 0; lt < 4; ++lt)
      #pragma unroll
      for (int nt2 = 0; nt2 < 2; ++nt2)
        o2[lt][nt2] = __builtin_amdgcn_mfma_f32_16x16x32_bf16(ap[lt][kt], vf[nt2][kt], o2[lt][nt2], 0, 0, 0);

  __syncthreads();   // barrier D: all waves done reading XQ/XK

  // ---------- AO (already normalized) -> LDS SW256(c,l) over dead XQ region ----------
  #pragma unroll
  for (int nt2 = 0; nt2 < 2; ++nt2) {
    const int c  = 32 * wv + 16 * nt2 + r;
    const int ab = (c >> 3) * 512 + (c & 7);
    #pragma unroll
    for (int lt = 0; lt < 4; ++lt) {
      const int lb = 16 * lt + quad * 4;
      AO[ab + (lb + 0) * 8] = f2bf(o2[lt][nt2][0]);
      AO[ab + (lb + 1) * 8] = f2bf(o2[lt][nt2][1]);
      AO[ab + (lb + 2) * 8] = f2bf(o2[lt][nt2][2]);
      AO[ab + (lb + 3) * 8] = f2bf(o2[lt][nt2][3]);
    }
  }
  __syncthreads();   // barrier E: AO complete for all heads

  // ---------- final projection: out = w_proj @ AO + b_proj, window scatter ----------
  {
    floatx4 acc[2][4];
    #pragma unroll
    for (int i = 0; i < 2; ++i)
      #pragma unroll
      for (int j = 0; j < 4; ++j) acc[i][j] = vzero;
    gemm_wx(WPp, 2 * wv, AO, quad, r, acc);
    #pragma unroll
    for (int mt = 0; mt < 2; ++mt) {
      const int ob = 32 * wv + 16 * mt + quad * 4;
      const float b0 = bproj[ob + 0], b1 = bproj[ob + 1];
      const float b2 = bproj[ob + 2], b3 = bproj[ob + 3];
      #pragma unroll
      for (int nt = 0; nt < 4; ++nt) {
        const int l  = 16 * nt + r;
        const int hh = h0 + (l >> 3);
        const int ww = w0 + (l & 7);
        if (hh < kH && ww < kW) {
          const int gi = (b * kC + ob) * kHW + hh * kW + ww;
          out[gi]           = acc[mt][nt][0] + b0;
          out[gi + kHW]     = acc[mt][nt][1] + b1;
          out[gi + 2 * kHW] = acc[mt][nt][2] + b2;
          out[gi + 3 * kHW] = acc[mt][nt][3] + b3;
        }
      }
    }
  }
}

extern "C" void kernel_launch(void* const* d_in, const int* in_sizes, int n_in,
                              void* d_out, int out_size, void* d_ws, size_t ws_size,
                              hipStream_t stream) {
  const float* xq    = (const float*)d_in[0];
  const float* xkv   = (const float*)d_in[1];
  const float* wq    = (const float*)d_in[2];
  const float* wkv   = (const float*)d_in[3];
  const float* wproj = (const float*)d_in[4];
  const float* bproj = (const float*)d_in[5];
  float* out = (float*)d_out;
  short* wpk = (short*)d_ws;   // 512 KB packed bf16 weights

  // Pre-pack weights to bf16 fragment order (re-run every launch; workspace may be poisoned).
  pack_w<<<1024, 256, 0, stream>>>(wq, wkv, wproj, wpk);

  // 64KB dynamic LDS per block -> 2 blocks/CU, 16 waves/CU (4 waves/SIMD).
  (void)hipFuncSetAttribute((const void*)win_attn,
                            hipFuncAttributeMaxDynamicSharedMemorySize, 65536);
  win_attn<<<4096, 512, 65536, stream>>>(xq, xkv, wpk, bproj, out);
}